// Round 10
// baseline (1347.768 us; speedup 1.0000x reference)
//
#include <hip/hip_runtime.h>
#include <hip/hip_fp16.h>
#include <cstdint>

#define H 64
#define EPR 16   // edges per round in gat (16 -> 4KB tile/wave)
#define NB 120   // partition blocks per graph (pass A/C chunking)

__device__ __forceinline__ float selu_f(float x) {
  const float sc = 1.0507009873554805f;
  const float al = 1.6732632423543772f;
  return x > 0.f ? sc * x : sc * al * (expf(x) - 1.f);
}

// ---------- GEMM v4: v3 minus the A-LDS stage (occupancy fix) ----------
// v3 used 51KB LDS/block -> 3 blocks/CU = 12 waves/CU static cap. The As tile
// is consumed only by 8 same-address lanes per element -> direct global float4
// loads hardware-merge to one transaction; unique traffic unchanged and A is
// L2/L3-resident. LDS 16.4KB -> ~8 blocks/CU; VGPR-capped ~20 waves/CU.
// 2-deep ping-pong prefetch hides L2/L3 latency. Summation order per output
// (bias init, ascending k, fmaf) identical to v3 -> bit-identical C.
__global__ __launch_bounds__(256) void gemm64_v4(
    const float* __restrict__ Au, const float* __restrict__ Am,
    const float* __restrict__ W0u, const float* __restrict__ b0u,
    const float* __restrict__ W1u, const float* __restrict__ b1u,
    const float* __restrict__ W0m, const float* __restrict__ b0m,
    const float* __restrict__ W1m, const float* __restrict__ b1m,
    __half* __restrict__ C0u, float* __restrict__ C1u,
    __half* __restrict__ C0m, float* __restrict__ C1m,
    int Nu, int Nm, int su, int sm) {
  __shared__ float Ws[64 * 64];
  __shared__ float bs[64];

  const int b = blockIdx.x;
  const float *A, *W, *bias; __half* Ch = nullptr; float* Cf = nullptr;
  int N, blk; bool half_out;
  if (b < su)             { A = Au; W = W0u; bias = b0u; Ch = C0u; N = Nu; blk = b;             half_out = true; }
  else if (b < 2 * su)    { A = Au; W = W1u; bias = b1u; Cf = C1u; N = Nu; blk = b - su;        half_out = false; }
  else if (b < 2*su + sm) { A = Am; W = W0m; bias = b0m; Ch = C0m; N = Nm; blk = b - 2*su;      half_out = true; }
  else                    { A = Am; W = W1m; bias = b1m; Cf = C1m; N = Nm; blk = b - 2*su - sm; half_out = false; }

  const int tid = threadIdx.x;
  for (int i = tid; i < 1024; i += 256) ((float4*)Ws)[i] = ((const float4*)W)[i];
  if (tid < 64) bs[tid] = bias[tid];
  __syncthreads();

  const int cg = tid & 7;   // 8-col group
  const int rs = tid >> 3;  // 0..31; rows rs + 32*i
  const int row0 = blk * 128;

  int rows[4]; const float* ap[4];
#pragma unroll
  for (int i = 0; i < 4; ++i) {
    rows[i] = row0 + rs + 32 * i;
    int ar = rows[i] < N ? rows[i] : (N - 1);  // clamped addr; result unsaved
    ap[i] = A + (size_t)ar * H;
  }

  float acc[4][8];
#pragma unroll
  for (int i = 0; i < 4; ++i)
#pragma unroll
    for (int j = 0; j < 8; ++j) acc[i][j] = bs[cg * 8 + j];

  float4 a4[4], a4n[4];
#pragma unroll
  for (int i = 0; i < 4; ++i) a4[i] = *(const float4*)(ap[i]);

  // process one kt given its row slices
  auto proc = [&](float4 (&aa)[4], int kt) {
#pragma unroll
    for (int kk = 0; kk < 4; ++kk) {
      const int k = kt * 4 + kk;
      const float4* wr = (const float4*)&Ws[k * 64 + cg * 8];
      float4 w0 = wr[0], w1 = wr[1];
      float a[4];
      a[0] = (kk == 0) ? aa[0].x : (kk == 1) ? aa[0].y : (kk == 2) ? aa[0].z : aa[0].w;
      a[1] = (kk == 0) ? aa[1].x : (kk == 1) ? aa[1].y : (kk == 2) ? aa[1].z : aa[1].w;
      a[2] = (kk == 0) ? aa[2].x : (kk == 1) ? aa[2].y : (kk == 2) ? aa[2].z : aa[2].w;
      a[3] = (kk == 0) ? aa[3].x : (kk == 1) ? aa[3].y : (kk == 2) ? aa[3].z : aa[3].w;
#pragma unroll
      for (int i = 0; i < 4; ++i) {
        acc[i][0] = fmaf(a[i], w0.x, acc[i][0]);
        acc[i][1] = fmaf(a[i], w0.y, acc[i][1]);
        acc[i][2] = fmaf(a[i], w0.z, acc[i][2]);
        acc[i][3] = fmaf(a[i], w0.w, acc[i][3]);
        acc[i][4] = fmaf(a[i], w1.x, acc[i][4]);
        acc[i][5] = fmaf(a[i], w1.y, acc[i][5]);
        acc[i][6] = fmaf(a[i], w1.z, acc[i][6]);
        acc[i][7] = fmaf(a[i], w1.w, acc[i][7]);
      }
    }
  };

#pragma unroll
  for (int kt = 0; kt < 16; kt += 2) {
    // prefetch kt+1 (always exists: kt max 14)
#pragma unroll
    for (int i = 0; i < 4; ++i) a4n[i] = *(const float4*)(ap[i] + (kt + 1) * 4);
    proc(a4, kt);
    if (kt + 2 < 16) {
#pragma unroll
      for (int i = 0; i < 4; ++i) a4[i] = *(const float4*)(ap[i] + (kt + 2) * 4);
    }
    proc(a4n, kt + 1);
  }

#pragma unroll
  for (int i = 0; i < 4; ++i) {
    const int row = rows[i];
    if (row >= N) continue;
    if (half_out) {
      unsigned pu[4];
#pragma unroll
      for (int j2 = 0; j2 < 4; ++j2) {
        __half2 t = __floats2half2_rn(acc[i][2 * j2], acc[i][2 * j2 + 1]);
        pu[j2] = *(unsigned*)&t;
      }
      *(uint4*)(Ch + (size_t)row * H + cg * 8) = make_uint4(pu[0], pu[1], pu[2], pu[3]);
    } else {
      float4* c1 = (float4*)(Cf + (size_t)row * H + cg * 8);
      c1[0] = make_float4(acc[i][0], acc[i][1], acc[i][2], acc[i][3]);
      c1[1] = make_float4(acc[i][4], acc[i][5], acc[i][6], acc[i][7]);
    }
  }
}

// ---------- Pass A: per-block bucket histograms (LDS only, no device atomics) ----------
__global__ __launch_bounds__(256) void bucket_hist(
    const int* __restrict__ ed1, int E1r, int n1e, int sh1, int B1, int* __restrict__ mat1,
    const int* __restrict__ ed2, int E2r, int n2e, int sh2, int B2, int* __restrict__ mat2) {
  __shared__ int hist[640];
  int b = blockIdx.x;
  const int* ed; int Er, ne, sh, Bn, blk; int* mat;
  if (b < NB) { ed = ed1; Er = E1r; ne = n1e; sh = sh1; Bn = B1; mat = mat1; blk = b; }
  else { ed = ed2; Er = E2r; ne = n2e; sh = sh2; Bn = B2; mat = mat2; blk = b - NB; }
  for (int i = threadIdx.x; i < Bn; i += 256) hist[i] = 0;
  __syncthreads();
  int chunk = (ne + NB - 1) / NB;
  int lo = blk * chunk, hi = lo + chunk;
  if (hi > ne) hi = ne;
  for (int e = lo + threadIdx.x; e < hi; e += 256) {
    int d = (e < Er) ? ed[e] : (e - Er);
    atomicAdd(&hist[d >> sh], 1);  // LDS atomic
  }
  __syncthreads();
  for (int i = threadIdx.x; i < Bn; i += 256) mat[(size_t)i * NB + blk] = hist[i];
}

// ---------- scan chain ----------
__global__ __launch_bounds__(256) void scan_partial2(
    const int* __restrict__ cnt1, int n1, int* __restrict__ psum1, int* __restrict__ bsum1,
    const int* __restrict__ cnt2, int n2, int* __restrict__ psum2, int* __restrict__ bsum2,
    int split) {
  __shared__ int sh[256];
  int b = blockIdx.x;
  const int* cnt; int n; int* psum; int* bsum; int lb;
  if (b < split) { cnt = cnt1; n = n1; psum = psum1; bsum = bsum1; lb = b; }
  else { cnt = cnt2; n = n2; psum = psum2; bsum = bsum2; lb = b - split; }
  int i = lb * 256 + threadIdx.x;
  int tid = threadIdx.x;
  sh[tid] = (i < n) ? cnt[i] : 0;
  __syncthreads();
  for (int off = 1; off < 256; off <<= 1) {
    int t = (tid >= off) ? sh[tid - off] : 0;
    __syncthreads();
    if (tid >= off) sh[tid] += t;
    __syncthreads();
  }
  if (i < n) psum[i] = sh[tid];
  if (tid == 255) bsum[lb] = sh[255];
}

__global__ __launch_bounds__(256) void scan_bsums2(
    int* __restrict__ bsum1, int nb1, int* __restrict__ bsum2, int nb2) {
  __shared__ int sh[256];
  const int tid = threadIdx.x;
  for (int which = 0; which < 2; ++which) {
    int* bsum = which ? bsum2 : bsum1;
    int nb = which ? nb2 : nb1;
    int run = 0;
    for (int start = 0; start < nb; start += 256) {
      int i = start + tid;
      int v = (i < nb) ? bsum[i] : 0;
      __syncthreads();
      sh[tid] = v;
      __syncthreads();
      for (int off = 1; off < 256; off <<= 1) {
        int t = (tid >= off) ? sh[tid - off] : 0;
        __syncthreads();
        if (tid >= off) sh[tid] += t;
        __syncthreads();
      }
      if (i < nb) bsum[i] = run + sh[tid] - v;  // exclusive
      run += sh[255];
      __syncthreads();
    }
  }
}

__global__ __launch_bounds__(256) void finalize_excl2(
    const int* __restrict__ cnt1, const int* __restrict__ psum1,
    const int* __restrict__ bsum1, int n1, int* __restrict__ excl1,
    const int* __restrict__ cnt2, const int* __restrict__ psum2,
    const int* __restrict__ bsum2, int n2, int* __restrict__ excl2, int split) {
  int b = blockIdx.x;
  const int *cnt, *psum, *bsum; int n; int* excl; int lb;
  if (b < split) { cnt = cnt1; psum = psum1; bsum = bsum1; n = n1; excl = excl1; lb = b; }
  else { cnt = cnt2; psum = psum2; bsum = bsum2; n = n2; excl = excl2; lb = b - split; }
  int i = lb * 256 + threadIdx.x;
  if (i >= n) return;
  excl[i] = psum[i] + bsum[lb] - cnt[i];
}

// ---------- Pass C: partition edges into bucket order via private LDS cursors ----------
__global__ __launch_bounds__(256) void bucket_part(
    const int* __restrict__ es1, const int* __restrict__ ed1, int E1r, int n1e,
    int sh1, int B1, const int* __restrict__ excl1, unsigned* __restrict__ part1,
    const int* __restrict__ es2, const int* __restrict__ ed2, int E2r, int n2e,
    int sh2, int B2, const int* __restrict__ excl2, unsigned* __restrict__ part2) {
  __shared__ int cur[640];
  int b = blockIdx.x;
  const int *es, *ed, *excl; int Er, ne, sh, Bn, blk; unsigned* part;
  if (b < NB) { es = es1; ed = ed1; Er = E1r; ne = n1e; sh = sh1; Bn = B1; excl = excl1; part = part1; blk = b; }
  else { es = es2; ed = ed2; Er = E2r; ne = n2e; sh = sh2; Bn = B2; excl = excl2; part = part2; blk = b - NB; }
  for (int i = threadIdx.x; i < Bn; i += 256) cur[i] = excl[(size_t)i * NB + blk];
  __syncthreads();
  int chunk = (ne + NB - 1) / NB;
  int lo = blk * chunk, hi = lo + chunk;
  if (hi > ne) hi = ne;
  const unsigned lmask = (1u << sh) - 1u;
  for (int e = lo + threadIdx.x; e < hi; e += 256) {
    int s, d;
    if (e < Er) { s = es[e]; d = ed[e]; } else { s = e - Er; d = s; }
    int bkt = d >> sh;
    int pos = atomicAdd(&cur[bkt], 1);  // LDS atomic; (block,bucket) ranges disjoint
    part[pos] = (((unsigned)d & lmask) << 18) | (unsigned)s;
  }
}

// ---------- Pass D: per-bucket LDS counting sort (R<=256) -> row_ptr + csr ----------
__global__ __launch_bounds__(256) void bucket_sort(
    const unsigned* __restrict__ part1, const int* __restrict__ excl1,
    int n1e, int sh1, int B1, int nd1, int* __restrict__ rp1, int* __restrict__ csr1,
    const unsigned* __restrict__ part2, const int* __restrict__ excl2,
    int n2e, int sh2, int B2, int nd2, int* __restrict__ rp2, int* __restrict__ csr2) {
  __shared__ int cnt_s[256];
  __shared__ int scan_s[256];
  int b = blockIdx.x;
  const unsigned* part; const int* excl; int ne, sh, Bn, nd, bkt; int *rp, *csr;
  if (b < B1) { part = part1; excl = excl1; ne = n1e; sh = sh1; Bn = B1; nd = nd1; rp = rp1; csr = csr1; bkt = b; }
  else { part = part2; excl = excl2; ne = n2e; sh = sh2; Bn = B2; nd = nd2; rp = rp2; csr = csr2; bkt = b - B1; }
  const int tid = threadIdx.x;
  const int dbase = bkt << sh;
  const int R = 1 << sh;          // <= 256
  int rcap = nd - dbase;
  if (rcap > R) rcap = R;
  const int base = excl[(size_t)bkt * NB];
  const int endv = (bkt == Bn - 1) ? ne : excl[(size_t)(bkt + 1) * NB];

  cnt_s[tid] = 0;
  __syncthreads();
  for (int i = base + tid; i < endv; i += 256)
    atomicAdd(&cnt_s[part[i] >> 18], 1);
  __syncthreads();
  int c = cnt_s[tid];
  scan_s[tid] = c;
  __syncthreads();
  for (int off = 1; off < 256; off <<= 1) {
    int t = (tid >= off) ? scan_s[tid - off] : 0;
    __syncthreads();
    if (tid >= off) scan_s[tid] += t;
    __syncthreads();
  }
  if (tid < rcap) rp[dbase + tid + 1] = base + scan_s[tid];
  cnt_s[tid] = base + scan_s[tid] - c;   // exclusive write cursor
  if (tid == 0 && bkt == 0) rp[0] = 0;
  __syncthreads();
  for (int i = base + tid; i < endv; i += 256) {
    unsigned p = part[i];
    int dl = p >> 18;
    int pos = atomicAdd(&cnt_s[dl], 1);  // LDS atomic
    csr[pos] = (int)(p & 0x3FFFFu);
  }
}

// ---------- merged fused GATv2: single-fetch, degree-specialized ----------
// (verified baseline kernel, unchanged: 110.2 us/dispatch; local optimum
// across 5 variants — dst3/dst4/WPB16/dst6 all regressed via residency loss)
__global__ __launch_bounds__(256) void gat_dst2(
    const int* __restrict__ rp1, const int* __restrict__ csr1,
    const __half* __restrict__ xl1, const float* __restrict__ xr1,
    const float* __restrict__ att1, const float* __restrict__ bias1,
    float* __restrict__ out1, int nd1,
    const int* __restrict__ rp2, const int* __restrict__ csr2,
    const __half* __restrict__ xl2, const float* __restrict__ xr2,
    const float* __restrict__ att2, const float* __restrict__ bias2,
    float* __restrict__ out2, int nd2, int split) {
  __shared__ __align__(16) float tile[4][EPR * 64];  // 4 waves x 4KB, private

  const int b = blockIdx.x;
  const int* rp; const int* csr; const __half* xl; const float *xr, *att, *bias;
  float* out; int nd, d0;
  if (b < split) {
    rp = rp1; csr = csr1; xl = xl1; xr = xr1; att = att1; bias = bias1;
    out = out1; nd = nd1; d0 = b * 4;
  } else {
    rp = rp2; csr = csr2; xl = xl2; xr = xr2; att = att2; bias = bias2;
    out = out2; nd = nd2; d0 = (b - split) * 4;
  }
  const int w = threadIdx.x >> 6;
  const int d = d0 + w;
  if (d >= nd) return;
  const int h = threadIdx.x & 63;
  const unsigned h2 = (unsigned)h * 2u;          // byte offset of feature h (fp16)
  const char* xlb = (const char*)xl;
  float* tl = tile[w];

  const float xr_h = xr[(size_t)d * H + h];
  const float a = att[h];
  const float a06 = 0.6f * a, a04 = 0.4f * a;
  const float bias_h = bias[h];
  // wave-uniform bounds -> SGPRs (enables s_load for csr index fetches)
  const int sbeg = __builtin_amdgcn_readfirstlane(rp[d]);
  const int send = __builtin_amdgcn_readfirstlane(rp[d + 1]);

  const int r = h & 15;          // transpose: my edge row
  const int q = h >> 4;          // quarter of that row
  const int pr = (q << 2) ^ r;   // xor piece for transpose reads

  float o;  // pre-activation output

  if (send - sbeg <= EPR) {
    // ================= fast path: single round, plain softmax =================
    const int cnt = send - sbeg;   // may be 0 (isolated dst) -> out = bias
    const int* csw = csr + sbeg;   // uniform base -> scalar loads
    float v[EPR];
#pragma unroll
    for (int qq = 0; qq < EPR / 4; ++qq) {
      if (qq * 4 < cnt) {  // wave-uniform
#pragma unroll
        for (int i = 0; i < 4; ++i) {
          const int k = qq * 4 + i;
          int j = k < cnt ? k : cnt - 1;   // uniform clamped dup
          unsigned src = (unsigned)csw[j]; // s_load (uniform addr)
          v[k] = __half2float(*(const __half*)(xlb + ((src << 7) | h2)));
        }
      }
    }
#pragma unroll
    for (int qq = 0; qq < EPR / 4; ++qq) {
      if (qq * 4 < cnt) {
#pragma unroll
        for (int i = 0; i < 4; ++i) {
          const int k = qq * 4 + i;
          float p = v[k] + xr_h;
          tl[(k << 6) | (h ^ (k << 2))] = fmaf(p, a06, fabsf(p) * a04);
        }
      }
    }
    const float4* t4 = (const float4*)tl;
    float t0 = 0.f, t1 = 0.f, t2 = 0.f, t3 = 0.f;
#pragma unroll
    for (int c = 0; c < 4; ++c) {
      float4 q4 = t4[(r << 4) | (pr ^ c)];
      t0 += q4.x; t1 += q4.y; t2 += q4.z; t3 += q4.w;
    }
    float t = (t0 + t1) + (t2 + t3);
    t += __shfl_xor(t, 16, 64);
    t += __shfl_xor(t, 32, 64);
    t = (r < cnt) ? t : -3.0e38f;

    float M = t;
#pragma unroll
    for (int mk = 1; mk <= 8; mk <<= 1) M = fmaxf(M, __shfl_xor(M, mk, 64));
    float e = __expf(t - M);
    float S = e;
#pragma unroll
    for (int mk = 1; mk <= 8; mk <<= 1) S += __shfl_xor(S, mk, 64);
    if (h < 16) tl[h] = e;

    float P = 0.f;
#pragma unroll
    for (int qq = 0; qq < EPR / 4; ++qq) {
      if (qq * 4 < cnt) {
        float4 w4 = ((const float4*)tl)[qq];
        P += w4.x * v[qq * 4 + 0];
        P += w4.y * v[qq * 4 + 1];
        P += w4.z * v[qq * 4 + 2];
        P += w4.w * v[qq * 4 + 3];
      }
    }
    o = P / (S + 1e-16f) + bias_h;
  } else {
    // ================= multi-round path: flash + ping-pong prefetch ===========
    float m = -3.0e38f, s = 0.f, acc = 0.f;
    int base = sbeg;               // uniform
    float v[EPR], v2[EPR];

    // prologue: first round is full (send-sbeg > EPR)
    {
      const int* csw = csr + base;
#pragma unroll
      for (int k = 0; k < EPR; ++k) {
        unsigned src = (unsigned)csw[k];   // s_load
        v[k] = __half2float(*(const __half*)(xlb + ((src << 7) | h2)));
      }
    }

    // one round: consume vc (cnt edges at base), prefetch into vp
    auto round = [&](float (&vc)[EPR], float (&vp)[EPR]) -> bool {
      int cnt = send - base;
      if (cnt > EPR) cnt = EPR;
#pragma unroll
      for (int qq = 0; qq < EPR / 4; ++qq) {
        if (qq * 4 < cnt) {
#pragma unroll
          for (int i = 0; i < 4; ++i) {
            const int k = qq * 4 + i;
            float p = vc[k] + xr_h;
            tl[(k << 6) | (h ^ (k << 2))] = fmaf(p, a06, fabsf(p) * a04);
          }
        }
      }
      // prefetch next round (overlaps softmax chain below)
      const int nbase = base + EPR;
      int ncnt = send - nbase;
      const bool have_next = ncnt > 0;
      if (ncnt > EPR) ncnt = EPR;
      if (have_next) {
        const int* csn = csr + nbase;      // uniform base -> scalar loads
#pragma unroll
        for (int qq = 0; qq < EPR / 4; ++qq) {
          if (qq * 4 < ncnt) {
#pragma unroll
            for (int i = 0; i < 4; ++i) {
              const int k = qq * 4 + i;
              int j = k < ncnt ? k : ncnt - 1;
              unsigned src = (unsigned)csn[j];
              vp[k] = __half2float(*(const __half*)(xlb + ((src << 7) | h2)));
            }
          }
        }
      }
      const float4* t4 = (const float4*)tl;
      float t0 = 0.f, t1 = 0.f, t2 = 0.f, t3 = 0.f;
#pragma unroll
      for (int c = 0; c < 4; ++c) {
        float4 q4 = t4[(r << 4) | (pr ^ c)];
        t0 += q4.x; t1 += q4.y; t2 += q4.z; t3 += q4.w;
      }
      float t = (t0 + t1) + (t2 + t3);
      t += __shfl_xor(t, 16, 64);
      t += __shfl_xor(t, 32, 64);
      t = (r < cnt) ? t : -3.0e38f;

      float M = t;
#pragma unroll
      for (int mk = 1; mk <= 8; mk <<= 1) M = fmaxf(M, __shfl_xor(M, mk, 64));
      float e = __expf(t - M);
      float S = e;
#pragma unroll
      for (int mk = 1; mk <= 8; mk <<= 1) S += __shfl_xor(S, mk, 64);
      if (h < 16) tl[h] = e;

      float nm = fmaxf(m, M);
      float a_old = __expf(m - nm);
      float a_new = __expf(M - nm);
      float P = 0.f;
#pragma unroll
      for (int qq = 0; qq < EPR / 4; ++qq) {
        if (qq * 4 < cnt) {
          float4 w4 = ((const float4*)tl)[qq];
          P += w4.x * vc[qq * 4 + 0];
          P += w4.y * vc[qq * 4 + 1];
          P += w4.z * vc[qq * 4 + 2];
          P += w4.w * vc[qq * 4 + 3];
        }
      }
      s = s * a_old + S * a_new;
      acc = acc * a_old + P * a_new;
      m = nm;
      base = nbase;
      return have_next;
    };

    for (;;) {
      if (!round(v, v2)) break;   // consume v, prefetch v2
      if (!round(v2, v)) break;   // consume v2, prefetch v
    }
    o = acc / (s + 1e-16f) + bias_h;
  }

  out[(size_t)d * H + h] = selu_f(o);
}

// ---------- launch ----------
extern "C" void kernel_launch(void* const* d_in, const int* in_sizes, int n_in,
                              void* d_out, int out_size, void* d_ws, size_t ws_size,
                              hipStream_t stream) {
  const float* x_user = (const float*)d_in[0];
  const float* x_movie = (const float*)d_in[1];
  const int* e_u2m = (const int*)d_in[2];
  const int* e_m2u = (const int*)d_in[3];
  const float* Wl = (const float*)d_in[4];
  const float* bl = (const float*)d_in[5];
  const float* Wr = (const float*)d_in[6];
  const float* br = (const float*)d_in[7];
  const float* att = (const float*)d_in[8];
  const float* bias = (const float*)d_in[9];

  const int n_user = in_sizes[0] / H;
  const int n_movie = in_sizes[1] / H;
  const int E1 = in_sizes[2] / 2;  // user->movie (dst = movie)
  const int E2 = in_sizes[3] / 2;  // movie->user (dst = user)
  const int n_loop = n_user < n_movie ? n_user : n_movie;
  const int nE1 = E1 + n_loop;
  const int nE2 = E2 + n_loop;

  // smaller buckets -> 4x more pass-D blocks (SHM 5: 32 dsts, SHU 8: 256 dsts)
  const int SHM = 5, SHU = 8;
  const int Bm = (n_movie + (1 << SHM) - 1) >> SHM;   // ~625
  const int Bu = (n_user + (1 << SHU) - 1) >> SHU;    // ~391
  const int nmatM = Bm * NB, nmatU = Bu * NB;
  const int nbm = (nmatM + 255) / 256, nbu = (nmatU + 255) / 256;

  float* ws = (float*)d_ws;
  size_t o = 0;
  __half* xl_u2m = (__half*)(ws + o); o += (size_t)n_user * H / 2;
  __half* xl_m2u = (__half*)(ws + o); o += (size_t)n_movie * H / 2;
  float* xr_u2m = ws + o; o += (size_t)n_movie * H;
  float* xr_m2u = ws + o; o += (size_t)n_user * H;

  int* matM  = (int*)(ws + o); o += nmatM;
  int* psumM = (int*)(ws + o); o += nmatM;
  int* exclM = (int*)(ws + o); o += nmatM;
  int* matU  = (int*)(ws + o); o += nmatU;
  int* psumU = (int*)(ws + o); o += nmatU;
  int* exclU = (int*)(ws + o); o += nmatU;
  int* bsumM = (int*)(ws + o); o += 1024;
  int* bsumU = (int*)(ws + o); o += 1024;
  unsigned* partM = (unsigned*)(ws + o); o += nE1;
  unsigned* partU = (unsigned*)(ws + o); o += nE2;
  int* csr1 = (int*)(ws + o); o += nE1;
  int* csr2 = (int*)(ws + o); o += nE2;
  int* rp1  = (int*)(ws + o); o += n_movie + 1;
  int* rp2  = (int*)(ws + o); o += n_user + 1;

  float* out_u = (float*)d_out;
  float* out_m = out_u + (size_t)n_user * H;

  const int su = (n_user + 127) / 128;
  const int sm = (n_movie + 127) / 128;
  const int split1 = (n_movie + 3) / 4;   // gat: movie blocks (long, launch first)
  const int split2 = (n_user + 3) / 4;    // gat: user blocks

  // ---- CSR build: deterministic two-level bucket sort, zero device atomics ----
  bucket_hist<<<2 * NB, 256, 0, stream>>>(
      e_u2m + E1, E1, nE1, SHM, Bm, matM,
      e_m2u + E2, E2, nE2, SHU, Bu, matU);
  scan_partial2<<<nbm + nbu, 256, 0, stream>>>(
      matM, nmatM, psumM, bsumM, matU, nmatU, psumU, bsumU, nbm);
  scan_bsums2<<<1, 256, 0, stream>>>(bsumM, nbm, bsumU, nbu);
  finalize_excl2<<<nbm + nbu, 256, 0, stream>>>(
      matM, psumM, bsumM, nmatM, exclM,
      matU, psumU, bsumU, nmatU, exclU, nbm);
  bucket_part<<<2 * NB, 256, 0, stream>>>(
      e_u2m, e_u2m + E1, E1, nE1, SHM, Bm, exclM, partM,
      e_m2u, e_m2u + E2, E2, nE2, SHU, Bu, exclU, partU);
  bucket_sort<<<Bm + Bu, 256, 0, stream>>>(
      partM, exclM, nE1, SHM, Bm, n_movie, rp1, csr1,
      partU, exclU, nE2, SHU, Bu, n_user, rp2, csr2);

  for (int l = 0; l < 2; ++l) {
    const float* cu = (l == 0) ? x_user : out_u;
    const float* cm = (l == 0) ? x_movie : out_m;
    const int p0 = l * 2 + 0;  // user->movie params
    const int p1 = l * 2 + 1;  // movie->user params

    gemm64_v4<<<2 * (su + sm), 256, 0, stream>>>(
        cu, cm,
        Wl + (size_t)p0 * H * H, bl + (size_t)p0 * H,   // user C0 = Wl[p0] (fp16)
        Wr + (size_t)p1 * H * H, br + (size_t)p1 * H,   // user C1 = Wr[p1] (fp32)
        Wl + (size_t)p1 * H * H, bl + (size_t)p1 * H,   // movie C0 = Wl[p1] (fp16)
        Wr + (size_t)p0 * H * H, br + (size_t)p0 * H,   // movie C1 = Wr[p0] (fp32)
        xl_u2m, xr_m2u, xl_m2u, xr_u2m,
        n_user, n_movie, su, sm);

    gat_dst2<<<split1 + split2, 256, 0, stream>>>(
        rp1, csr1, xl_u2m, xr_u2m, att + (size_t)p0 * H, bias + (size_t)p0 * H,
        out_m, n_movie,
        rp2, csr2, xl_m2u, xr_m2u, att + (size_t)p1 * H, bias + (size_t)p1 * H,
        out_u, n_user, split1);
  }
}

// Round 12
// 432.692 us; speedup vs baseline: 3.1148x; 3.1148x over previous
//
#include <hip/hip_runtime.h>
#include <hip/hip_fp16.h>
#include <cstdint>

#define H 64
#define EPR 16   // edges per round in gat (16 -> 4KB tile/wave)
#define NB 120   // partition blocks per graph (pass A/C chunking)

__device__ __forceinline__ float selu_f(float x) {
  const float sc = 1.0507009873554805f;
  const float al = 1.6732632423543772f;
  return x > 0.f ? sc * x : sc * al * (expf(x) - 1.f);
}

// ---------- GEMM v3: 128 rows/block, 8 col-groups x 4 rows/thread ----------
// (verified round 7: best gemm variant, ~80 us/launch. v4 (no A-LDS, direct
// global + prefetch) regressed to 503 us: VGPR 256 -> occ 11%, spill traffic.)
__global__ __launch_bounds__(256) void gemm64_v3(
    const float* __restrict__ Au, const float* __restrict__ Am,
    const float* __restrict__ W0u, const float* __restrict__ b0u,
    const float* __restrict__ W1u, const float* __restrict__ b1u,
    const float* __restrict__ W0m, const float* __restrict__ b0m,
    const float* __restrict__ W1m, const float* __restrict__ b1m,
    __half* __restrict__ C0u, float* __restrict__ C1u,
    __half* __restrict__ C0m, float* __restrict__ C1m,
    int Nu, int Nm, int su, int sm) {
  __shared__ float Ws[64 * 64];
  __shared__ float As[128 * 68];   // stride 68: 16B-aligned rows, conflict-free
  __shared__ float bs[64];

  const int b = blockIdx.x;
  const float *A, *W, *bias; __half* Ch = nullptr; float* Cf = nullptr;
  int N, blk; bool half_out;
  if (b < su)             { A = Au; W = W0u; bias = b0u; Ch = C0u; N = Nu; blk = b;             half_out = true; }
  else if (b < 2 * su)    { A = Au; W = W1u; bias = b1u; Cf = C1u; N = Nu; blk = b - su;        half_out = false; }
  else if (b < 2*su + sm) { A = Am; W = W0m; bias = b0m; Ch = C0m; N = Nm; blk = b - 2*su;      half_out = true; }
  else                    { A = Am; W = W1m; bias = b1m; Cf = C1m; N = Nm; blk = b - 2*su - sm; half_out = false; }

  const int tid = threadIdx.x;
  for (int i = tid; i < 1024; i += 256) ((float4*)Ws)[i] = ((const float4*)W)[i];
  if (tid < 64) bs[tid] = bias[tid];

  const int row0 = blk * 128;
  for (int i = tid; i < 2048; i += 256) {
    int r = i >> 4, c4 = i & 15;
    int row = row0 + r;
    float4 v = make_float4(0.f, 0.f, 0.f, 0.f);
    if (row < N) v = ((const float4*)(A + (size_t)row * H))[c4];
    *(float4*)&As[r * 68 + c4 * 4] = v;
  }
  __syncthreads();

  const int cg = tid & 7;   // 8-col group
  const int rs = tid >> 3;  // 0..31; rows rs + 32*i
  float acc[4][8];
#pragma unroll
  for (int i = 0; i < 4; ++i)
#pragma unroll
    for (int j = 0; j < 8; ++j) acc[i][j] = bs[cg * 8 + j];

  for (int kt = 0; kt < 16; ++kt) {
    float4 a4[4];
#pragma unroll
    for (int i = 0; i < 4; ++i)
      a4[i] = *(const float4*)&As[(rs + 32 * i) * 68 + kt * 4];
#pragma unroll
    for (int kk = 0; kk < 4; ++kk) {
      const int k = kt * 4 + kk;
      const float4* wr = (const float4*)&Ws[k * 64 + cg * 8];
      float4 w0 = wr[0], w1 = wr[1];
      float a[4];
      a[0] = (kk == 0) ? a4[0].x : (kk == 1) ? a4[0].y : (kk == 2) ? a4[0].z : a4[0].w;
      a[1] = (kk == 0) ? a4[1].x : (kk == 1) ? a4[1].y : (kk == 2) ? a4[1].z : a4[1].w;
      a[2] = (kk == 0) ? a4[2].x : (kk == 1) ? a4[2].y : (kk == 2) ? a4[2].z : a4[2].w;
      a[3] = (kk == 0) ? a4[3].x : (kk == 1) ? a4[3].y : (kk == 2) ? a4[3].z : a4[3].w;
#pragma unroll
      for (int i = 0; i < 4; ++i) {
        acc[i][0] = fmaf(a[i], w0.x, acc[i][0]);
        acc[i][1] = fmaf(a[i], w0.y, acc[i][1]);
        acc[i][2] = fmaf(a[i], w0.z, acc[i][2]);
        acc[i][3] = fmaf(a[i], w0.w, acc[i][3]);
        acc[i][4] = fmaf(a[i], w1.x, acc[i][4]);
        acc[i][5] = fmaf(a[i], w1.y, acc[i][5]);
        acc[i][6] = fmaf(a[i], w1.z, acc[i][6]);
        acc[i][7] = fmaf(a[i], w1.w, acc[i][7]);
      }
    }
  }

#pragma unroll
  for (int i = 0; i < 4; ++i) {
    const int row = row0 + rs + 32 * i;
    if (row >= N) continue;
    if (half_out) {
      unsigned pu[4];
#pragma unroll
      for (int j2 = 0; j2 < 4; ++j2) {
        __half2 t = __floats2half2_rn(acc[i][2 * j2], acc[i][2 * j2 + 1]);
        pu[j2] = *(unsigned*)&t;
      }
      *(uint4*)(Ch + (size_t)row * H + cg * 8) = make_uint4(pu[0], pu[1], pu[2], pu[3]);
    } else {
      float4* c1 = (float4*)(Cf + (size_t)row * H + cg * 8);
      c1[0] = make_float4(acc[i][0], acc[i][1], acc[i][2], acc[i][3]);
      c1[1] = make_float4(acc[i][4], acc[i][5], acc[i][6], acc[i][7]);
    }
  }
}

// ---------- Pass A: per-block bucket histograms (LDS only, no device atomics) ----------
__global__ __launch_bounds__(256) void bucket_hist(
    const int* __restrict__ ed1, int E1r, int n1e, int sh1, int B1, int* __restrict__ mat1,
    const int* __restrict__ ed2, int E2r, int n2e, int sh2, int B2, int* __restrict__ mat2) {
  __shared__ int hist[640];
  int b = blockIdx.x;
  const int* ed; int Er, ne, sh, Bn, blk; int* mat;
  if (b < NB) { ed = ed1; Er = E1r; ne = n1e; sh = sh1; Bn = B1; mat = mat1; blk = b; }
  else { ed = ed2; Er = E2r; ne = n2e; sh = sh2; Bn = B2; mat = mat2; blk = b - NB; }
  for (int i = threadIdx.x; i < Bn; i += 256) hist[i] = 0;
  __syncthreads();
  int chunk = (ne + NB - 1) / NB;
  int lo = blk * chunk, hi = lo + chunk;
  if (hi > ne) hi = ne;
  for (int e = lo + threadIdx.x; e < hi; e += 256) {
    int d = (e < Er) ? ed[e] : (e - Er);
    atomicAdd(&hist[d >> sh], 1);  // LDS atomic
  }
  __syncthreads();
  for (int i = threadIdx.x; i < Bn; i += 256) mat[(size_t)i * NB + blk] = hist[i];
}

// ---------- scan chain ----------
__global__ __launch_bounds__(256) void scan_partial2(
    const int* __restrict__ cnt1, int n1, int* __restrict__ psum1, int* __restrict__ bsum1,
    const int* __restrict__ cnt2, int n2, int* __restrict__ psum2, int* __restrict__ bsum2,
    int split) {
  __shared__ int sh[256];
  int b = blockIdx.x;
  const int* cnt; int n; int* psum; int* bsum; int lb;
  if (b < split) { cnt = cnt1; n = n1; psum = psum1; bsum = bsum1; lb = b; }
  else { cnt = cnt2; n = n2; psum = psum2; bsum = bsum2; lb = b - split; }
  int i = lb * 256 + threadIdx.x;
  int tid = threadIdx.x;
  sh[tid] = (i < n) ? cnt[i] : 0;
  __syncthreads();
  for (int off = 1; off < 256; off <<= 1) {
    int t = (tid >= off) ? sh[tid - off] : 0;
    __syncthreads();
    if (tid >= off) sh[tid] += t;
    __syncthreads();
  }
  if (i < n) psum[i] = sh[tid];
  if (tid == 255) bsum[lb] = sh[255];
}

__global__ __launch_bounds__(256) void scan_bsums2(
    int* __restrict__ bsum1, int nb1, int* __restrict__ bsum2, int nb2) {
  __shared__ int sh[256];
  const int tid = threadIdx.x;
  for (int which = 0; which < 2; ++which) {
    int* bsum = which ? bsum2 : bsum1;
    int nb = which ? nb2 : nb1;
    int run = 0;
    for (int start = 0; start < nb; start += 256) {
      int i = start + tid;
      int v = (i < nb) ? bsum[i] : 0;
      __syncthreads();
      sh[tid] = v;
      __syncthreads();
      for (int off = 1; off < 256; off <<= 1) {
        int t = (tid >= off) ? sh[tid - off] : 0;
        __syncthreads();
        if (tid >= off) sh[tid] += t;
        __syncthreads();
      }
      if (i < nb) bsum[i] = run + sh[tid] - v;  // exclusive
      run += sh[255];
      __syncthreads();
    }
  }
}

__global__ __launch_bounds__(256) void finalize_excl2(
    const int* __restrict__ cnt1, const int* __restrict__ psum1,
    const int* __restrict__ bsum1, int n1, int* __restrict__ excl1,
    const int* __restrict__ cnt2, const int* __restrict__ psum2,
    const int* __restrict__ bsum2, int n2, int* __restrict__ excl2, int split) {
  int b = blockIdx.x;
  const int *cnt, *psum, *bsum; int n; int* excl; int lb;
  if (b < split) { cnt = cnt1; psum = psum1; bsum = bsum1; n = n1; excl = excl1; lb = b; }
  else { cnt = cnt2; psum = psum2; bsum = bsum2; n = n2; excl = excl2; lb = b - split; }
  int i = lb * 256 + threadIdx.x;
  if (i >= n) return;
  excl[i] = psum[i] + bsum[lb] - cnt[i];
}

// ---------- Pass C: partition edges into bucket order via private LDS cursors ----------
__global__ __launch_bounds__(256) void bucket_part(
    const int* __restrict__ es1, const int* __restrict__ ed1, int E1r, int n1e,
    int sh1, int B1, const int* __restrict__ excl1, unsigned* __restrict__ part1,
    const int* __restrict__ es2, const int* __restrict__ ed2, int E2r, int n2e,
    int sh2, int B2, const int* __restrict__ excl2, unsigned* __restrict__ part2) {
  __shared__ int cur[640];
  int b = blockIdx.x;
  const int *es, *ed, *excl; int Er, ne, sh, Bn, blk; unsigned* part;
  if (b < NB) { es = es1; ed = ed1; Er = E1r; ne = n1e; sh = sh1; Bn = B1; excl = excl1; part = part1; blk = b; }
  else { es = es2; ed = ed2; Er = E2r; ne = n2e; sh = sh2; Bn = B2; excl = excl2; part = part2; blk = b - NB; }
  for (int i = threadIdx.x; i < Bn; i += 256) cur[i] = excl[(size_t)i * NB + blk];
  __syncthreads();
  int chunk = (ne + NB - 1) / NB;
  int lo = blk * chunk, hi = lo + chunk;
  if (hi > ne) hi = ne;
  const unsigned lmask = (1u << sh) - 1u;
  for (int e = lo + threadIdx.x; e < hi; e += 256) {
    int s, d;
    if (e < Er) { s = es[e]; d = ed[e]; } else { s = e - Er; d = s; }
    int bkt = d >> sh;
    int pos = atomicAdd(&cur[bkt], 1);  // LDS atomic; (block,bucket) ranges disjoint
    part[pos] = (((unsigned)d & lmask) << 18) | (unsigned)s;
  }
}

// ---------- Pass D: per-bucket LDS counting sort (R<=256) -> row_ptr + csr ----------
__global__ __launch_bounds__(256) void bucket_sort(
    const unsigned* __restrict__ part1, const int* __restrict__ excl1,
    int n1e, int sh1, int B1, int nd1, int* __restrict__ rp1, int* __restrict__ csr1,
    const unsigned* __restrict__ part2, const int* __restrict__ excl2,
    int n2e, int sh2, int B2, int nd2, int* __restrict__ rp2, int* __restrict__ csr2) {
  __shared__ int cnt_s[256];
  __shared__ int scan_s[256];
  int b = blockIdx.x;
  const unsigned* part; const int* excl; int ne, sh, Bn, nd, bkt; int *rp, *csr;
  if (b < B1) { part = part1; excl = excl1; ne = n1e; sh = sh1; Bn = B1; nd = nd1; rp = rp1; csr = csr1; bkt = b; }
  else { part = part2; excl = excl2; ne = n2e; sh = sh2; Bn = B2; nd = nd2; rp = rp2; csr = csr2; bkt = b - B1; }
  const int tid = threadIdx.x;
  const int dbase = bkt << sh;
  const int R = 1 << sh;          // <= 256
  int rcap = nd - dbase;
  if (rcap > R) rcap = R;
  const int base = excl[(size_t)bkt * NB];
  const int endv = (bkt == Bn - 1) ? ne : excl[(size_t)(bkt + 1) * NB];

  cnt_s[tid] = 0;
  __syncthreads();
  for (int i = base + tid; i < endv; i += 256)
    atomicAdd(&cnt_s[part[i] >> 18], 1);
  __syncthreads();
  int c = cnt_s[tid];
  scan_s[tid] = c;
  __syncthreads();
  for (int off = 1; off < 256; off <<= 1) {
    int t = (tid >= off) ? scan_s[tid - off] : 0;
    __syncthreads();
    if (tid >= off) scan_s[tid] += t;
    __syncthreads();
  }
  if (tid < rcap) rp[dbase + tid + 1] = base + scan_s[tid];
  cnt_s[tid] = base + scan_s[tid] - c;   // exclusive write cursor
  if (tid == 0 && bkt == 0) rp[0] = 0;
  __syncthreads();
  for (int i = base + tid; i < endv; i += 256) {
    unsigned p = part[i];
    int dl = p >> 18;
    int pos = atomicAdd(&cnt_s[dl], 1);  // LDS atomic
    csr[pos] = (int)(p & 0x3FFFFu);
  }
}

// ---------- merged fused GATv2: single-fetch, degree-specialized ----------
// (verified baseline kernel, unchanged: 110.2 us/dispatch; local optimum
// across 5 variants — dst3/dst4/WPB16/dst6 all regressed via residency loss)
__global__ __launch_bounds__(256) void gat_dst2(
    const int* __restrict__ rp1, const int* __restrict__ csr1,
    const __half* __restrict__ xl1, const float* __restrict__ xr1,
    const float* __restrict__ att1, const float* __restrict__ bias1,
    float* __restrict__ out1, int nd1,
    const int* __restrict__ rp2, const int* __restrict__ csr2,
    const __half* __restrict__ xl2, const float* __restrict__ xr2,
    const float* __restrict__ att2, const float* __restrict__ bias2,
    float* __restrict__ out2, int nd2, int split) {
  __shared__ __align__(16) float tile[4][EPR * 64];  // 4 waves x 4KB, private

  const int b = blockIdx.x;
  const int* rp; const int* csr; const __half* xl; const float *xr, *att, *bias;
  float* out; int nd, d0;
  if (b < split) {
    rp = rp1; csr = csr1; xl = xl1; xr = xr1; att = att1; bias = bias1;
    out = out1; nd = nd1; d0 = b * 4;
  } else {
    rp = rp2; csr = csr2; xl = xl2; xr = xr2; att = att2; bias = bias2;
    out = out2; nd = nd2; d0 = (b - split) * 4;
  }
  const int w = threadIdx.x >> 6;
  const int d = d0 + w;
  if (d >= nd) return;
  const int h = threadIdx.x & 63;
  const unsigned h2 = (unsigned)h * 2u;          // byte offset of feature h (fp16)
  const char* xlb = (const char*)xl;
  float* tl = tile[w];

  const float xr_h = xr[(size_t)d * H + h];
  const float a = att[h];
  const float a06 = 0.6f * a, a04 = 0.4f * a;
  const float bias_h = bias[h];
  // wave-uniform bounds -> SGPRs (enables s_load for csr index fetches)
  const int sbeg = __builtin_amdgcn_readfirstlane(rp[d]);
  const int send = __builtin_amdgcn_readfirstlane(rp[d + 1]);

  const int r = h & 15;          // transpose: my edge row
  const int q = h >> 4;          // quarter of that row
  const int pr = (q << 2) ^ r;   // xor piece for transpose reads

  float o;  // pre-activation output

  if (send - sbeg <= EPR) {
    // ================= fast path: single round, plain softmax =================
    const int cnt = send - sbeg;   // may be 0 (isolated dst) -> out = bias
    const int* csw = csr + sbeg;   // uniform base -> scalar loads
    float v[EPR];
#pragma unroll
    for (int qq = 0; qq < EPR / 4; ++qq) {
      if (qq * 4 < cnt) {  // wave-uniform
#pragma unroll
        for (int i = 0; i < 4; ++i) {
          const int k = qq * 4 + i;
          int j = k < cnt ? k : cnt - 1;   // uniform clamped dup
          unsigned src = (unsigned)csw[j]; // s_load (uniform addr)
          v[k] = __half2float(*(const __half*)(xlb + ((src << 7) | h2)));
        }
      }
    }
#pragma unroll
    for (int qq = 0; qq < EPR / 4; ++qq) {
      if (qq * 4 < cnt) {
#pragma unroll
        for (int i = 0; i < 4; ++i) {
          const int k = qq * 4 + i;
          float p = v[k] + xr_h;
          tl[(k << 6) | (h ^ (k << 2))] = fmaf(p, a06, fabsf(p) * a04);
        }
      }
    }
    const float4* t4 = (const float4*)tl;
    float t0 = 0.f, t1 = 0.f, t2 = 0.f, t3 = 0.f;
#pragma unroll
    for (int c = 0; c < 4; ++c) {
      float4 q4 = t4[(r << 4) | (pr ^ c)];
      t0 += q4.x; t1 += q4.y; t2 += q4.z; t3 += q4.w;
    }
    float t = (t0 + t1) + (t2 + t3);
    t += __shfl_xor(t, 16, 64);
    t += __shfl_xor(t, 32, 64);
    t = (r < cnt) ? t : -3.0e38f;

    float M = t;
#pragma unroll
    for (int mk = 1; mk <= 8; mk <<= 1) M = fmaxf(M, __shfl_xor(M, mk, 64));
    float e = __expf(t - M);
    float S = e;
#pragma unroll
    for (int mk = 1; mk <= 8; mk <<= 1) S += __shfl_xor(S, mk, 64);
    if (h < 16) tl[h] = e;

    float P = 0.f;
#pragma unroll
    for (int qq = 0; qq < EPR / 4; ++qq) {
      if (qq * 4 < cnt) {
        float4 w4 = ((const float4*)tl)[qq];
        P += w4.x * v[qq * 4 + 0];
        P += w4.y * v[qq * 4 + 1];
        P += w4.z * v[qq * 4 + 2];
        P += w4.w * v[qq * 4 + 3];
      }
    }
    o = P / (S + 1e-16f) + bias_h;
  } else {
    // ================= multi-round path: flash + ping-pong prefetch ===========
    float m = -3.0e38f, s = 0.f, acc = 0.f;
    int base = sbeg;               // uniform
    float v[EPR], v2[EPR];

    // prologue: first round is full (send-sbeg > EPR)
    {
      const int* csw = csr + base;
#pragma unroll
      for (int k = 0; k < EPR; ++k) {
        unsigned src = (unsigned)csw[k];   // s_load
        v[k] = __half2float(*(const __half*)(xlb + ((src << 7) | h2)));
      }
    }

    // one round: consume vc (cnt edges at base), prefetch into vp
    auto round = [&](float (&vc)[EPR], float (&vp)[EPR]) -> bool {
      int cnt = send - base;
      if (cnt > EPR) cnt = EPR;
#pragma unroll
      for (int qq = 0; qq < EPR / 4; ++qq) {
        if (qq * 4 < cnt) {
#pragma unroll
          for (int i = 0; i < 4; ++i) {
            const int k = qq * 4 + i;
            float p = vc[k] + xr_h;
            tl[(k << 6) | (h ^ (k << 2))] = fmaf(p, a06, fabsf(p) * a04);
          }
        }
      }
      // prefetch next round (overlaps softmax chain below)
      const int nbase = base + EPR;
      int ncnt = send - nbase;
      const bool have_next = ncnt > 0;
      if (ncnt > EPR) ncnt = EPR;
      if (have_next) {
        const int* csn = csr + nbase;      // uniform base -> scalar loads
#pragma unroll
        for (int qq = 0; qq < EPR / 4; ++qq) {
          if (qq * 4 < ncnt) {
#pragma unroll
            for (int i = 0; i < 4; ++i) {
              const int k = qq * 4 + i;
              int j = k < ncnt ? k : ncnt - 1;
              unsigned src = (unsigned)csn[j];
              vp[k] = __half2float(*(const __half*)(xlb + ((src << 7) | h2)));
            }
          }
        }
      }
      const float4* t4 = (const float4*)tl;
      float t0 = 0.f, t1 = 0.f, t2 = 0.f, t3 = 0.f;
#pragma unroll
      for (int c = 0; c < 4; ++c) {
        float4 q4 = t4[(r << 4) | (pr ^ c)];
        t0 += q4.x; t1 += q4.y; t2 += q4.z; t3 += q4.w;
      }
      float t = (t0 + t1) + (t2 + t3);
      t += __shfl_xor(t, 16, 64);
      t += __shfl_xor(t, 32, 64);
      t = (r < cnt) ? t : -3.0e38f;

      float M = t;
#pragma unroll
      for (int mk = 1; mk <= 8; mk <<= 1) M = fmaxf(M, __shfl_xor(M, mk, 64));
      float e = __expf(t - M);
      float S = e;
#pragma unroll
      for (int mk = 1; mk <= 8; mk <<= 1) S += __shfl_xor(S, mk, 64);
      if (h < 16) tl[h] = e;

      float nm = fmaxf(m, M);
      float a_old = __expf(m - nm);
      float a_new = __expf(M - nm);
      float P = 0.f;
#pragma unroll
      for (int qq = 0; qq < EPR / 4; ++qq) {
        if (qq * 4 < cnt) {
          float4 w4 = ((const float4*)tl)[qq];
          P += w4.x * vc[qq * 4 + 0];
          P += w4.y * vc[qq * 4 + 1];
          P += w4.z * vc[qq * 4 + 2];
          P += w4.w * vc[qq * 4 + 3];
        }
      }
      s = s * a_old + S * a_new;
      acc = acc * a_old + P * a_new;
      m = nm;
      base = nbase;
      return have_next;
    };

    for (;;) {
      if (!round(v, v2)) break;   // consume v, prefetch v2
      if (!round(v2, v)) break;   // consume v2, prefetch v
    }
    o = acc / (s + 1e-16f) + bias_h;
  }

  out[(size_t)d * H + h] = selu_f(o);
}

// ---------- launch ----------
extern "C" void kernel_launch(void* const* d_in, const int* in_sizes, int n_in,
                              void* d_out, int out_size, void* d_ws, size_t ws_size,
                              hipStream_t stream) {
  const float* x_user = (const float*)d_in[0];
  const float* x_movie = (const float*)d_in[1];
  const int* e_u2m = (const int*)d_in[2];
  const int* e_m2u = (const int*)d_in[3];
  const float* Wl = (const float*)d_in[4];
  const float* bl = (const float*)d_in[5];
  const float* Wr = (const float*)d_in[6];
  const float* br = (const float*)d_in[7];
  const float* att = (const float*)d_in[8];
  const float* bias = (const float*)d_in[9];

  const int n_user = in_sizes[0] / H;
  const int n_movie = in_sizes[1] / H;
  const int E1 = in_sizes[2] / 2;  // user->movie (dst = movie)
  const int E2 = in_sizes[3] / 2;  // movie->user (dst = user)
  const int n_loop = n_user < n_movie ? n_user : n_movie;
  const int nE1 = E1 + n_loop;
  const int nE2 = E2 + n_loop;

  // smaller buckets -> 4x more pass-D blocks (SHM 5: 32 dsts, SHU 8: 256 dsts)
  const int SHM = 5, SHU = 8;
  const int Bm = (n_movie + (1 << SHM) - 1) >> SHM;   // ~625
  const int Bu = (n_user + (1 << SHU) - 1) >> SHU;    // ~391
  const int nmatM = Bm * NB, nmatU = Bu * NB;
  const int nbm = (nmatM + 255) / 256, nbu = (nmatU + 255) / 256;

  float* ws = (float*)d_ws;
  size_t o = 0;
  __half* xl_u2m = (__half*)(ws + o); o += (size_t)n_user * H / 2;
  __half* xl_m2u = (__half*)(ws + o); o += (size_t)n_movie * H / 2;
  float* xr_u2m = ws + o; o += (size_t)n_movie * H;
  float* xr_m2u = ws + o; o += (size_t)n_user * H;

  int* matM  = (int*)(ws + o); o += nmatM;
  int* psumM = (int*)(ws + o); o += nmatM;
  int* exclM = (int*)(ws + o); o += nmatM;
  int* matU  = (int*)(ws + o); o += nmatU;
  int* psumU = (int*)(ws + o); o += nmatU;
  int* exclU = (int*)(ws + o); o += nmatU;
  int* bsumM = (int*)(ws + o); o += 1024;
  int* bsumU = (int*)(ws + o); o += 1024;
  unsigned* partM = (unsigned*)(ws + o); o += nE1;
  unsigned* partU = (unsigned*)(ws + o); o += nE2;
  int* csr1 = (int*)(ws + o); o += nE1;
  int* csr2 = (int*)(ws + o); o += nE2;
  int* rp1  = (int*)(ws + o); o += n_movie + 1;
  int* rp2  = (int*)(ws + o); o += n_user + 1;

  float* out_u = (float*)d_out;
  float* out_m = out_u + (size_t)n_user * H;

  const int su = (n_user + 127) / 128;
  const int sm = (n_movie + 127) / 128;
  const int split1 = (n_movie + 3) / 4;   // gat: movie blocks (long, launch first)
  const int split2 = (n_user + 3) / 4;    // gat: user blocks

  // ---- CSR build: deterministic two-level bucket sort, zero device atomics ----
  bucket_hist<<<2 * NB, 256, 0, stream>>>(
      e_u2m + E1, E1, nE1, SHM, Bm, matM,
      e_m2u + E2, E2, nE2, SHU, Bu, matU);
  scan_partial2<<<nbm + nbu, 256, 0, stream>>>(
      matM, nmatM, psumM, bsumM, matU, nmatU, psumU, bsumU, nbm);
  scan_bsums2<<<1, 256, 0, stream>>>(bsumM, nbm, bsumU, nbu);
  finalize_excl2<<<nbm + nbu, 256, 0, stream>>>(
      matM, psumM, bsumM, nmatM, exclM,
      matU, psumU, bsumU, nmatU, exclU, nbm);
  bucket_part<<<2 * NB, 256, 0, stream>>>(
      e_u2m, e_u2m + E1, E1, nE1, SHM, Bm, exclM, partM,
      e_m2u, e_m2u + E2, E2, nE2, SHU, Bu, exclU, partU);
  bucket_sort<<<Bm + Bu, 256, 0, stream>>>(
      partM, exclM, nE1, SHM, Bm, n_movie, rp1, csr1,
      partU, exclU, nE2, SHU, Bu, n_user, rp2, csr2);

  for (int l = 0; l < 2; ++l) {
    const float* cu = (l == 0) ? x_user : out_u;
    const float* cm = (l == 0) ? x_movie : out_m;
    const int p0 = l * 2 + 0;  // user->movie params
    const int p1 = l * 2 + 1;  // movie->user params

    gemm64_v3<<<2 * (su + sm), 256, 0, stream>>>(
        cu, cm,
        Wl + (size_t)p0 * H * H, bl + (size_t)p0 * H,   // user C0 = Wl[p0] (fp16)
        Wr + (size_t)p1 * H * H, br + (size_t)p1 * H,   // user C1 = Wr[p1] (fp32)
        Wl + (size_t)p1 * H * H, bl + (size_t)p1 * H,   // movie C0 = Wl[p1] (fp16)
        Wr + (size_t)p0 * H * H, br + (size_t)p0 * H,   // movie C1 = Wr[p0] (fp32)
        xl_u2m, xr_m2u, xl_m2u, xr_u2m,
        n_user, n_movie, su, sm);

    gat_dst2<<<split1 + split2, 256, 0, stream>>>(
        rp1, csr1, xl_u2m, xr_u2m, att + (size_t)p0 * H, bias + (size_t)p0 * H,
        out_m, n_movie,
        rp2, csr2, xl_m2u, xr_m2u, att + (size_t)p1 * H, bias + (size_t)p1 * H,
        out_u, n_user, split1);
  }
}